// Round 1
// baseline (1013.346 us; speedup 1.0000x reference)
//
#include <hip/hip_runtime.h>

// Problem dims
#define B_    16384
#define A_    32
#define SLOT_ 64
#define H1_   256
#define H2_   128
#define L_    32

// ---------------- LDS layout (floats) for the fused main kernel ----------------
// Live ranges are disjoint in time; regions are reused across phases.
#define ST_O   0        // s^T tile      64 k x 32 r            [0,2048)       phase L1
#define W1_O   2048     // W1^T dbuf  2 x (16 k x 256 n)        [2048,10240)   phase L1
#define H1T_O  0        // h1^T          256 k x 36 (32r+pad)   [0,9216)       phase L2 (after L1)
#define SSH_O  9216     // Sigma_inv     32 x 32                [9216,10240)   phase L3b
#define W2_O   10240    // W2^T dbuf  2 x (16 k x 128 n)        [10240,14336)  phase L2
#define H2T_O  0        // h2^T          128 k x 36             [0,4608)       phase L3a (after L2)
#define WMU_O  4608     // Wmu^T         128 k x 32 n           [4608,8704)    phase L3a (after L2)
#define DIF_O  10240    // diff^T        32 x 36                [10240,11392)  phase L3b (after L3a)
#define LDS_FL 14336    // 57,344 bytes -> 2 blocks/CU

__device__ __forceinline__ void gll16(const float* g, float* l) {
  // async global->LDS, 16B per lane; LDS dest is wave-uniform-base + lane*16 (linear mapping)
  __builtin_amdgcn_global_load_lds(
      (const __attribute__((address_space(1))) unsigned int*)g,
      (__attribute__((address_space(3))) unsigned int*)l, 16, 0, 0);
}

__device__ __forceinline__ void LD4(float d[4], const float* p) {
  float4 v = *(const float4*)p;
  d[0] = v.x; d[1] = v.y; d[2] = v.z; d[3] = v.w;
}
__device__ __forceinline__ void ST4(float* p, float a, float b, float c, float d) {
  float4 v; v.x = a; v.y = b; v.z = c; v.w = d;
  *(float4*)p = v;
}

// ---------------- P1: transpose s (B x 64) -> sT (64 x B) ----------------
__global__ __launch_bounds__(256) void transpose_s(const float* __restrict__ s,
                                                   float* __restrict__ sT) {
  __shared__ float t[64 * 65];
  const int b0 = blockIdx.x * 64, tid = threadIdx.x;
#pragma unroll
  for (int i = 0; i < 16; ++i) {
    int idx = i * 256 + tid;
    int r = idx >> 6, k = idx & 63;
    t[k * 65 + r] = s[(b0 + r) * SLOT_ + k];      // coalesced read
  }
  __syncthreads();
#pragma unroll
  for (int i = 0; i < 16; ++i) {
    int idx = i * 256 + tid;
    int k = idx >> 6, r = idx & 63;
    sT[k * B_ + b0 + r] = t[k * 65 + r];          // coalesced write
  }
}

// ---------------- P2: per-agent weight transposes to k-major ----------------
__global__ __launch_bounds__(256) void prep_weights(const float* __restrict__ W1,
                                                    const float* __restrict__ W2,
                                                    const float* __restrict__ Wmu,
                                                    float* __restrict__ W1T,
                                                    float* __restrict__ W2T,
                                                    float* __restrict__ WmuT) {
  __shared__ float t[64 * 65];
  const int a = blockIdx.x, tid = threadIdx.x;

  // W1[a]: (256 n, 64 k) -> W1T[a]: (64 k, 256 n)
  const float* w1 = W1 + a * H1_ * SLOT_;
  float* w1t = W1T + a * SLOT_ * H1_;
  for (int c = 0; c < 4; ++c) {
#pragma unroll
    for (int i = 0; i < 16; ++i) {
      int idx = i * 256 + tid; int r = idx >> 6, k = idx & 63;
      t[k * 65 + r] = w1[(c * 64 + r) * SLOT_ + k];
    }
    __syncthreads();
#pragma unroll
    for (int i = 0; i < 16; ++i) {
      int idx = i * 256 + tid; int k = idx >> 6, r = idx & 63;
      w1t[k * H1_ + c * 64 + r] = t[k * 65 + r];
    }
    __syncthreads();
  }

  // W2[a]: (128 n, 256 k) -> W2T[a]: (256 k, 128 n)
  const float* w2 = W2 + a * H2_ * H1_;
  float* w2t = W2T + a * H1_ * H2_;
  for (int cn = 0; cn < 2; ++cn)
    for (int ck = 0; ck < 4; ++ck) {
#pragma unroll
      for (int i = 0; i < 16; ++i) {
        int idx = i * 256 + tid; int r = idx >> 6, k = idx & 63;
        t[k * 65 + r] = w2[(cn * 64 + r) * H1_ + ck * 64 + k];
      }
      __syncthreads();
#pragma unroll
      for (int i = 0; i < 16; ++i) {
        int idx = i * 256 + tid; int k = idx >> 6, r = idx & 63;
        w2t[(ck * 64 + k) * H2_ + cn * 64 + r] = t[k * 65 + r];
      }
      __syncthreads();
    }

  // Wmu[a]: (32 n, 128 k) -> WmuT[a]: (128 k, 32 n)
  const float* wm = Wmu + a * L_ * H2_;
  float* wmt = WmuT + a * H2_ * L_;
  for (int ck = 0; ck < 2; ++ck) {
#pragma unroll
    for (int i = 0; i < 8; ++i) {
      int idx = i * 256 + tid; int r = idx >> 6, k = idx & 63;   // r<32
      t[k * 65 + r] = wm[r * H2_ + ck * 64 + k];
    }
    __syncthreads();
#pragma unroll
    for (int i = 0; i < 8; ++i) {
      int idx = i * 256 + tid; int k = idx >> 5, r = idx & 31;   // k<64
      wmt[(ck * 64 + k) * L_ + r] = t[k * 65 + r];
    }
    __syncthreads();
  }
}

// ---------------- Fused main: L1 -> L2 -> mu/diff -> Mahalanobis ----------------
// One block = one agent x 32 batch rows. 256 threads: tn = tid&31 (N dim), tm = tid>>5 (M dim).
__global__ __launch_bounds__(256, 2) void vae_main(
    const float* __restrict__ sTg, const float* __restrict__ W1Tg,
    const float* __restrict__ W2Tg, const float* __restrict__ WmuTg,
    const float* __restrict__ b1g, const float* __restrict__ b2g,
    const float* __restrict__ bmug, const float* __restrict__ musg,
    const float* __restrict__ Sig, float* __restrict__ out) {
  __shared__ __align__(16) float lds[LDS_FL];
  const int tid = threadIdx.x;
  const int tn = tid & 31, tm = tid >> 5;
  const int r0 = tm * 4;        // 4 batch rows per thread
  const int n0 = tn * 4;        // 4 output cols per thread (per 128-col group)

  // XCD-aware swizzle: blockIdx%8 == XCD. Each XCD owns 4 agents (tile-major inside),
  // so its weight working set (~830 KB) stays L2-resident. 16384 % 8 == 0 -> bijective.
  const int bid = blockIdx.x;
  const int xcd = bid & 7, idx = bid >> 3;          // idx in [0,2048)
  const int a = xcd * 4 + (idx & 3);
  const int tile = idx >> 2;                         // [0,512)
  const int b0 = tile * 32;

  // ---- issue all async staging / register prefetches up front ----
  // sT tile (2048 floats): linear [k][r]
#pragma unroll
  for (int i = 0; i < 2; ++i) {
    int i4 = i * 256 + tid;                // dwordx4 index
    int k = i4 >> 3, rq = i4 & 7;
    gll16(sTg + k * B_ + b0 + rq * 4, &lds[ST_O + i4 * 4]);
  }
  // W1^T chunk 0 (K=16 -> 4096 floats)
#pragma unroll
  for (int i = 0; i < 4; ++i) {
    int i4 = i * 256 + tid;
    gll16(W1Tg + a * (SLOT_ * H1_) + i4 * 4, &lds[W1_O + i4 * 4]);
  }
  // register prefetches (written to LDS later, T14 issue-early/write-late)
  float wmu_r[4][4];
#pragma unroll
  for (int i = 0; i < 4; ++i) LD4(wmu_r[i], WmuTg + a * (H2_ * L_) + (i * 256 + tid) * 4);
  float ssh_r[4];
  LD4(ssh_r, Sig + a * (L_ * L_) + tid * 4);
  float b1v[8];
  LD4(&b1v[0], b1g + a * H1_ + n0);
  LD4(&b1v[4], b1g + a * H1_ + 128 + n0);
  float b2v[4];
  LD4(b2v, b2g + a * H2_ + n0);
  const float bmu_v = bmug[a * L_ + tn];
  const float mus_v = musg[a * L_ + tn];

  __syncthreads();   // drains vmcnt: sT + W1 chunk0 resident

  // ---------------- L1: h1(32x256) = relu(s(32x64) @ W1T(64x256) + b1) ----------------
  float acc1[8][4];  // [col g*4+j][row m]
#pragma unroll
  for (int j = 0; j < 8; ++j)
#pragma unroll
    for (int m = 0; m < 4; ++m) acc1[j][m] = 0.f;

  for (int c = 0; c < 4; ++c) {           // K chunks of 16, double-buffered
    if (c < 3) {
#pragma unroll
      for (int i = 0; i < 4; ++i) {
        int i4 = i * 256 + tid;
        gll16(W1Tg + a * (SLOT_ * H1_) + (c + 1) * 4096 + i4 * 4,
              &lds[W1_O + ((c + 1) & 1) * 4096 + i4 * 4]);
      }
    }
    const float* wb = &lds[W1_O + (c & 1) * 4096];
#pragma unroll
    for (int kk = 0; kk < 16; ++kk) {
      const int k = c * 16 + kk;
      float a_[4], bb0[4], bb1[4];
      LD4(a_, &lds[ST_O + k * 32 + r0]);         // broadcast across tn
      LD4(bb0, &wb[kk * 256 + n0]);
      LD4(bb1, &wb[kk * 256 + 128 + n0]);
#pragma unroll
      for (int j = 0; j < 4; ++j)
#pragma unroll
        for (int m = 0; m < 4; ++m) {
          acc1[j][m]     += a_[m] * bb0[j];
          acc1[4 + j][m] += a_[m] * bb1[j];
        }
    }
    __syncthreads();   // buffer reuse + next chunk resident
  }

  // write h1^T (k-major, stride 36 to keep 16B-aligned b128 reads), stage Sigma, W2 chunk0
#pragma unroll
  for (int i = 0; i < 2; ++i) {            // W2^T chunk0 (2048 floats)
    int i4 = i * 256 + tid;
    gll16(W2Tg + a * (H1_ * H2_) + i4 * 4, &lds[W2_O + i4 * 4]);
  }
#pragma unroll
  for (int g = 0; g < 2; ++g)
#pragma unroll
    for (int j = 0; j < 4; ++j) {
      const int n = g * 128 + n0 + j;
      const float bias = b1v[g * 4 + j];
      ST4(&lds[H1T_O + n * 36 + r0],
          fmaxf(acc1[g * 4 + j][0] + bias, 0.f), fmaxf(acc1[g * 4 + j][1] + bias, 0.f),
          fmaxf(acc1[g * 4 + j][2] + bias, 0.f), fmaxf(acc1[g * 4 + j][3] + bias, 0.f));
    }
  ST4(&lds[SSH_O + tid * 4], ssh_r[0], ssh_r[1], ssh_r[2], ssh_r[3]);
  __syncthreads();

  // ---------------- L2: h2(32x128) = relu(h1 @ W2T(256x128) + b2) ----------------
  float acc2[4][4];
#pragma unroll
  for (int j = 0; j < 4; ++j)
#pragma unroll
    for (int m = 0; m < 4; ++m) acc2[j][m] = 0.f;

  for (int c = 0; c < 16; ++c) {          // K chunks of 16, double-buffered
    if (c < 15) {
#pragma unroll
      for (int i = 0; i < 2; ++i) {
        int i4 = i * 256 + tid;
        gll16(W2Tg + a * (H1_ * H2_) + (c + 1) * 2048 + i4 * 4,
              &lds[W2_O + ((c + 1) & 1) * 2048 + i4 * 4]);
      }
    }
    const float* wb = &lds[W2_O + (c & 1) * 2048];
#pragma unroll
    for (int kk = 0; kk < 16; ++kk) {
      const int k2 = c * 16 + kk;
      float a_[4], bb[4];
      LD4(a_, &lds[H1T_O + k2 * 36 + r0]);
      LD4(bb, &wb[kk * 128 + n0]);
#pragma unroll
      for (int j = 0; j < 4; ++j)
#pragma unroll
        for (int m = 0; m < 4; ++m) acc2[j][m] += a_[m] * bb[j];
    }
    __syncthreads();
  }

  // write h2^T and Wmu^T (from prefetched regs) over dead h1^T region
#pragma unroll
  for (int j = 0; j < 4; ++j) {
    const int n = n0 + j;
    const float bias = b2v[j];
    ST4(&lds[H2T_O + n * 36 + r0],
        fmaxf(acc2[j][0] + bias, 0.f), fmaxf(acc2[j][1] + bias, 0.f),
        fmaxf(acc2[j][2] + bias, 0.f), fmaxf(acc2[j][3] + bias, 0.f));
  }
#pragma unroll
  for (int i = 0; i < 4; ++i)
    ST4(&lds[WMU_O + (i * 256 + tid) * 4], wmu_r[i][0], wmu_r[i][1], wmu_r[i][2], wmu_r[i][3]);
  __syncthreads();

  // ---------------- L3a: mu(32x32) = h2 @ WmuT(128x32) + bmu ; diff = mu - mu_stats ----------------
  float acc3[4] = {0.f, 0.f, 0.f, 0.f};
#pragma unroll 4
  for (int k3 = 0; k3 < 128; ++k3) {
    float a_[4];
    LD4(a_, &lds[H2T_O + k3 * 36 + r0]);
    const float bv = lds[WMU_O + k3 * 32 + tn];
#pragma unroll
    for (int m = 0; m < 4; ++m) acc3[m] += a_[m] * bv;
  }
  float diff[4];
#pragma unroll
  for (int m = 0; m < 4; ++m) diff[m] = acc3[m] + bmu_v - mus_v;
  ST4(&lds[DIF_O + tn * 36 + r0], diff[0], diff[1], diff[2], diff[3]);
  __syncthreads();

  // ---------------- L3b: left = diff @ Sigma_inv ; score = -sum(left*diff) ----------------
  float z[4] = {0.f, 0.f, 0.f, 0.f};
#pragma unroll
  for (int l = 0; l < 32; ++l) {
    float a_[4];
    LD4(a_, &lds[DIF_O + l * 36 + r0]);
    const float sv = lds[SSH_O + l * 32 + tn];
#pragma unroll
    for (int m = 0; m < 4; ++m) z[m] += a_[m] * sv;
  }
  float p[4];
#pragma unroll
  for (int m = 0; m < 4; ++m) p[m] = z[m] * diff[m];
  // reduce across tn (32 lanes; masks <32 never cross the tm boundary inside a wave)
#pragma unroll
  for (int mask = 1; mask <= 16; mask <<= 1)
#pragma unroll
    for (int m = 0; m < 4; ++m) p[m] += __shfl_xor(p[m], mask, 64);
  if (tn == 0) {
#pragma unroll
    for (int m = 0; m < 4; ++m) out[(b0 + r0 + m) * A_ + a] = -p[m];
  }
}

// ---------------- K2: top-1 + threshold routing ----------------
__global__ __launch_bounds__(256) void route_argmax(const float* __restrict__ scores,
                                                    const float* __restrict__ theta,
                                                    float* __restrict__ assigned) {
  const int tid = threadIdx.x;
  const int b = blockIdx.x * 64 + (tid >> 2);
  const int q = tid & 3;                      // 4 threads per row, 8 agents each
  const float* row = scores + b * A_ + q * 8;
  float4 v0 = *(const float4*)row;
  float4 v1 = *(const float4*)(row + 4);
  float vals[8] = {v0.x, v0.y, v0.z, v0.w, v1.x, v1.y, v1.z, v1.w};
  float best = vals[0];
  int bi = q * 8;
#pragma unroll
  for (int j = 1; j < 8; ++j)
    if (vals[j] > best) { best = vals[j]; bi = q * 8 + j; }   // strict > : first max wins
#pragma unroll
  for (int m = 1; m <= 2; m <<= 1) {
    float ov = __shfl_xor(best, m, 64);
    int oi = __shfl_xor(bi, m, 64);
    if (ov > best || (ov == best && oi < bi)) { best = ov; bi = oi; }
  }
  if (q == 0) assigned[b] = (best >= theta[0]) ? (float)bi : -1.0f;
}

extern "C" void kernel_launch(void* const* d_in, const int* in_sizes, int n_in,
                              void* d_out, int out_size, void* d_ws, size_t ws_size,
                              hipStream_t stream) {
  const float* s    = (const float*)d_in[0];
  const float* W1   = (const float*)d_in[1];
  const float* b1   = (const float*)d_in[2];
  const float* W2   = (const float*)d_in[3];
  const float* b2   = (const float*)d_in[4];
  const float* Wmu  = (const float*)d_in[5];
  const float* bmu  = (const float*)d_in[6];
  const float* mus  = (const float*)d_in[7];
  const float* Sig  = (const float*)d_in[8];
  const float* th   = (const float*)d_in[9];
  float* out = (float*)d_out;

  // workspace layout (floats): sT | W1T | W2T | WmuT   (~10.5 MB total)
  float* sTg   = (float*)d_ws;
  float* W1Tg  = sTg + (size_t)SLOT_ * B_;           // 1,048,576
  float* W2Tg  = W1Tg + (size_t)A_ * SLOT_ * H1_;    //   524,288
  float* WmuTg = W2Tg + (size_t)A_ * H1_ * H2_;      // 1,048,576
  (void)ws_size; (void)in_sizes; (void)n_in; (void)out_size;

  transpose_s<<<B_ / 64, 256, 0, stream>>>(s, sTg);
  prep_weights<<<A_, 256, 0, stream>>>(W1, W2, Wmu, W1Tg, W2Tg, WmuTg);
  vae_main<<<(B_ / 32) * A_, 256, 0, stream>>>(sTg, W1Tg, W2Tg, WmuTg,
                                               b1, b2, bmu, mus, Sig, out);
  route_argmax<<<B_ / 64, 256, 0, stream>>>(out, th, out + (size_t)B_ * A_);
}

// Round 2
// 559.021 us; speedup vs baseline: 1.8127x; 1.8127x over previous
//
#include <hip/hip_runtime.h>

// Problem dims
#define B_  16384
#define A_  32

typedef _Float16 f16;
typedef __attribute__((ext_vector_type(8))) _Float16 half8;
typedef __attribute__((ext_vector_type(4))) float f32x4;

struct __align__(8) H4 { f16 a, b, c, d; };

__device__ __forceinline__ f32x4 MFMA(half8 a, half8 b, f32x4 c) {
  return __builtin_amdgcn_mfma_f32_16x16x32_f16(a, b, c, 0, 0, 0);
}

__device__ __forceinline__ void split1(float v, f16& h, f16& l) {
  h = (f16)v;
  l = (f16)(v - (float)h);   // exact residual (Sterbenz), then RN to f16
}

// ---------------- prep: split fp32 -> (hi, lo) f16 planes ----------------
__global__ __launch_bounds__(256) void split4(const float4* __restrict__ x,
                                              H4* __restrict__ hi, H4* __restrict__ lo,
                                              int n4) {
  int i = blockIdx.x * 256 + threadIdx.x;
  if (i >= n4) return;
  float4 v = x[i];
  H4 h, l;
  split1(v.x, h.a, l.a);
  split1(v.y, h.b, l.b);
  split1(v.z, h.c, l.c);
  split1(v.w, h.d, l.d);
  hi[i] = h; lo[i] = l;
}

// ---------------- fused main (MFMA, transposed formulation) ----------------
// One block = one agent x 32 batch cols. 256 threads = 4 waves.
// L1: C1^T(256x32) = W1(256x64) @ s^T(64x32)     wave w: rows 64w..64w+63
// L2: C2^T(128x32) = W2(128x256) @ h1^T           wave w: rows 32w..32w+31
// L3: mu^T(32x32)  = Wmu(32x128) @ h2^T           wave w: tile (rt3=w&1, ct3=w>>1)
// S : left^T(32x32)= Sigma(32x32) @ diff^T        same tile; score = -colsum(left*diff)
// All A-operands (weights) and s load straight from global to fragment regs.
// Only h1/h2/diff round-trip LDS (overlaid regions, XOR-bit4 swizzle).
__global__ __launch_bounds__(256, 3) void vae_main(
    const f16* __restrict__ sh, const f16* __restrict__ sl,
    const f16* __restrict__ w1h, const f16* __restrict__ w1l,
    const f16* __restrict__ w2h, const f16* __restrict__ w2l,
    const f16* __restrict__ wmh, const f16* __restrict__ wml,
    const f16* __restrict__ sgh, const f16* __restrict__ sgl,
    const float* __restrict__ b1g, const float* __restrict__ b2g,
    const float* __restrict__ bmug, const float* __restrict__ musg,
    float* __restrict__ out) {
  __shared__ __align__(16) char smem[32768];
  char* const h1hB = smem;                 // h1 hi [32 c][256 n] f16, swizzled (16 KB)
  char* const h1lB = smem + 16384;         // h1 lo
  char* const h2hB = smem;                 // overlay after L2: h2 hi [32][128] (8 KB)
  char* const h2lB = smem + 8192;          // h2 lo
  char* const dfhB = smem + 16384;         // overlay: diff hi [32 c][40 pad] (2560 B)
  char* const dflB = smem + 16384 + 2560;  // diff lo
  float* const part = (float*)(smem + 16384 + 5120);  // [4][16] score partials

  const int tid = threadIdx.x;
  const int l   = tid & 63;
  const int w   = tid >> 6;
  const int ln  = l & 15;    // row/col-within-16-tile (A row, B col, C col)
  const int g   = l >> 4;    // k-octet group (k0 = 8g); C rows = 4g..4g+3

  // XCD-aware swizzle: 4 agents per XCD, tile-major inside. 16384 % 8 == 0.
  const int bid  = blockIdx.x;
  const int a    = (bid & 7) * 4 + ((bid >> 3) & 3);
  const int tile = bid >> 5;                 // [0,512)
  const int b0   = tile * 32;

  // ---------------- L1 ----------------
  half8 sB[2][2][2];   // [ct][kc][hi/lo] B-frags, live for all of L1
#pragma unroll
  for (int ct = 0; ct < 2; ++ct)
#pragma unroll
    for (int kc = 0; kc < 2; ++kc) {
      const int off = (b0 + 16 * ct + ln) * 64 + 8 * g + 32 * kc;
      sB[ct][kc][0] = *(const half8*)(sh + off);
      sB[ct][kc][1] = *(const half8*)(sl + off);
    }
  f32x4 b1v[4];
#pragma unroll
  for (int rt = 0; rt < 4; ++rt)
    b1v[rt] = *(const f32x4*)(b1g + a * 256 + 64 * w + 16 * rt + 4 * g);

  f32x4 acc1[4][2];
#pragma unroll
  for (int rt = 0; rt < 4; ++rt)
#pragma unroll
    for (int ct = 0; ct < 2; ++ct) acc1[rt][ct] = (f32x4){0.f, 0.f, 0.f, 0.f};

  const int w1base = a * 256 * 64;
#pragma unroll
  for (int kc = 0; kc < 2; ++kc) {
    half8 A1h[4], A1l[4];
#pragma unroll
    for (int rt = 0; rt < 4; ++rt) {
      const int off = w1base + (64 * w + 16 * rt + ln) * 64 + 8 * g + 32 * kc;
      A1h[rt] = *(const half8*)(w1h + off);
      A1l[rt] = *(const half8*)(w1l + off);
    }
#pragma unroll
    for (int rt = 0; rt < 4; ++rt)
#pragma unroll
      for (int ct = 0; ct < 2; ++ct) {
        acc1[rt][ct] = MFMA(A1h[rt], sB[ct][kc][0], acc1[rt][ct]);
        acc1[rt][ct] = MFMA(A1h[rt], sB[ct][kc][1], acc1[rt][ct]);
        acc1[rt][ct] = MFMA(A1l[rt], sB[ct][kc][0], acc1[rt][ct]);
      }
  }

  // bias + relu + hi/lo split -> h1^T in LDS
#pragma unroll
  for (int rt = 0; rt < 4; ++rt)
#pragma unroll
    for (int ct = 0; ct < 2; ++ct) {
      const int c  = 16 * ct + ln;
      const int n0 = 64 * w + 16 * rt + 4 * g;
      const int ad = (c * 512 + n0 * 2) ^ ((c & 7) << 4);
      H4 hh, llo;
      float v0 = fmaxf(acc1[rt][ct][0] + b1v[rt][0], 0.f);
      float v1 = fmaxf(acc1[rt][ct][1] + b1v[rt][1], 0.f);
      float v2 = fmaxf(acc1[rt][ct][2] + b1v[rt][2], 0.f);
      float v3 = fmaxf(acc1[rt][ct][3] + b1v[rt][3], 0.f);
      split1(v0, hh.a, llo.a); split1(v1, hh.b, llo.b);
      split1(v2, hh.c, llo.c); split1(v3, hh.d, llo.d);
      *(H4*)(h1hB + ad) = hh;
      *(H4*)(h1lB + ad) = llo;
    }
  __syncthreads();

  // ---------------- L2 ----------------
  f32x4 acc2[2][2];
#pragma unroll
  for (int rt = 0; rt < 2; ++rt)
#pragma unroll
    for (int ct = 0; ct < 2; ++ct) acc2[rt][ct] = (f32x4){0.f, 0.f, 0.f, 0.f};
  f32x4 b2v[2];
#pragma unroll
  for (int rt = 0; rt < 2; ++rt)
    b2v[rt] = *(const f32x4*)(b2g + a * 128 + 32 * w + 16 * rt + 4 * g);

  const int w2base = a * 128 * 256;
#pragma unroll
  for (int kc = 0; kc < 8; ++kc) {
    half8 A2h[2], A2l[2], B2h[2], B2l[2];
#pragma unroll
    for (int rt = 0; rt < 2; ++rt) {
      const int off = w2base + (32 * w + 16 * rt + ln) * 256 + 8 * g + 32 * kc;
      A2h[rt] = *(const half8*)(w2h + off);
      A2l[rt] = *(const half8*)(w2l + off);
    }
#pragma unroll
    for (int ct = 0; ct < 2; ++ct) {
      const int c  = 16 * ct + ln;
      const int ad = (c * 512 + 16 * g + 64 * kc) ^ ((c & 7) << 4);
      B2h[ct] = *(const half8*)(h1hB + ad);
      B2l[ct] = *(const half8*)(h1lB + ad);
    }
#pragma unroll
    for (int rt = 0; rt < 2; ++rt)
#pragma unroll
      for (int ct = 0; ct < 2; ++ct) {
        acc2[rt][ct] = MFMA(A2h[rt], B2h[ct], acc2[rt][ct]);
        acc2[rt][ct] = MFMA(A2h[rt], B2l[ct], acc2[rt][ct]);
        acc2[rt][ct] = MFMA(A2l[rt], B2h[ct], acc2[rt][ct]);
      }
  }
  __syncthreads();   // all h1 reads done -> safe to overlay h2

#pragma unroll
  for (int rt = 0; rt < 2; ++rt)
#pragma unroll
    for (int ct = 0; ct < 2; ++ct) {
      const int c  = 16 * ct + ln;
      const int n0 = 32 * w + 16 * rt + 4 * g;
      const int ad = (c * 256 + n0 * 2) ^ ((c & 7) << 4);
      H4 hh, llo;
      float v0 = fmaxf(acc2[rt][ct][0] + b2v[rt][0], 0.f);
      float v1 = fmaxf(acc2[rt][ct][1] + b2v[rt][1], 0.f);
      float v2 = fmaxf(acc2[rt][ct][2] + b2v[rt][2], 0.f);
      float v3 = fmaxf(acc2[rt][ct][3] + b2v[rt][3], 0.f);
      split1(v0, hh.a, llo.a); split1(v1, hh.b, llo.b);
      split1(v2, hh.c, llo.c); split1(v3, hh.d, llo.d);
      *(H4*)(h2hB + ad) = hh;
      *(H4*)(h2lB + ad) = llo;
    }
  __syncthreads();

  // ---------------- L3: mu^T + diff ----------------
  const int rt3 = w & 1, ct3 = w >> 1;
  const int c3  = 16 * ct3 + ln;           // batch col for this wave's tile
  f32x4 acc3 = (f32x4){0.f, 0.f, 0.f, 0.f};
  const int wmbase = a * 32 * 128;
#pragma unroll
  for (int kc = 0; kc < 4; ++kc) {
    const int offA = wmbase + (16 * rt3 + ln) * 128 + 8 * g + 32 * kc;
    half8 Ah = *(const half8*)(wmh + offA);
    half8 Al = *(const half8*)(wml + offA);
    const int ad = (c3 * 256 + 16 * g + 64 * kc) ^ ((c3 & 7) << 4);
    half8 Bh = *(const half8*)(h2hB + ad);
    half8 Bl = *(const half8*)(h2lB + ad);
    acc3 = MFMA(Ah, Bh, acc3);
    acc3 = MFMA(Ah, Bl, acc3);
    acc3 = MFMA(Al, Bh, acc3);
  }
  const f32x4 bmuv = *(const f32x4*)(bmug + a * 32 + 16 * rt3 + 4 * g);
  const f32x4 musv = *(const f32x4*)(musg + a * 32 + 16 * rt3 + 4 * g);
  f32x4 dreg;
#pragma unroll
  for (int j = 0; j < 4; ++j) dreg[j] = acc3[j] + bmuv[j] - musv[j];
  {
    const int ad = c3 * 80 + (16 * rt3 + 4 * g) * 2;   // [32 c][40 f16] padded
    H4 hh, llo;
    split1(dreg[0], hh.a, llo.a); split1(dreg[1], hh.b, llo.b);
    split1(dreg[2], hh.c, llo.c); split1(dreg[3], hh.d, llo.d);
    *(H4*)(dfhB + ad) = hh;
    *(H4*)(dflB + ad) = llo;
  }
  __syncthreads();

  // ---------------- Sigma GEMM + score ----------------
  f32x4 accS = (f32x4){0.f, 0.f, 0.f, 0.f};
  {
    const int offA = a * 1024 + (16 * rt3 + ln) * 32 + 8 * g;   // Sigma symmetric
    half8 Ah = *(const half8*)(sgh + offA);
    half8 Al = *(const half8*)(sgl + offA);
    const int ad = c3 * 80 + 16 * g;
    half8 Bh = *(const half8*)(dfhB + ad);
    half8 Bl = *(const half8*)(dflB + ad);
    accS = MFMA(Ah, Bh, accS);
    accS = MFMA(Ah, Bl, accS);
    accS = MFMA(Al, Bh, accS);
  }
  // left and diff share the same C-fragment lane mapping -> dot in regs
  float p = accS[0] * dreg[0] + accS[1] * dreg[1] + accS[2] * dreg[2] + accS[3] * dreg[3];
  p += __shfl_xor(p, 16, 64);
  p += __shfl_xor(p, 32, 64);
  if (l < 16) part[w * 16 + ln] = p;   // partial over this wave's 16 latent rows
  __syncthreads();
  if (tid < 32) {
    const int i = tid & 15, cf = tid >> 4;
    const float sc = -(part[(cf * 2) * 16 + i] + part[(cf * 2 + 1) * 16 + i]);
    out[(size_t)(b0 + 16 * cf + i) * A_ + a] = sc;
  }
}

// ---------------- top-1 + threshold routing ----------------
__global__ __launch_bounds__(256) void route_argmax(const float* __restrict__ scores,
                                                    const float* __restrict__ theta,
                                                    float* __restrict__ assigned) {
  const int tid = threadIdx.x;
  const int b = blockIdx.x * 64 + (tid >> 2);
  const int q = tid & 3;                      // 4 threads per row, 8 agents each
  const float* row = scores + (size_t)b * A_ + q * 8;
  float4 v0 = *(const float4*)row;
  float4 v1 = *(const float4*)(row + 4);
  float vals[8] = {v0.x, v0.y, v0.z, v0.w, v1.x, v1.y, v1.z, v1.w};
  float best = vals[0];
  int bi = q * 8;
#pragma unroll
  for (int j = 1; j < 8; ++j)
    if (vals[j] > best) { best = vals[j]; bi = q * 8 + j; }   // strict > : first max wins
#pragma unroll
  for (int m = 1; m <= 2; m <<= 1) {
    float ov = __shfl_xor(best, m, 64);
    int oi = __shfl_xor(bi, m, 64);
    if (ov > best || (ov == best && oi < bi)) { best = ov; bi = oi; }
  }
  if (q == 0) assigned[b] = (best >= theta[0]) ? (float)bi : -1.0f;
}

extern "C" void kernel_launch(void* const* d_in, const int* in_sizes, int n_in,
                              void* d_out, int out_size, void* d_ws, size_t ws_size,
                              hipStream_t stream) {
  const float* s   = (const float*)d_in[0];
  const float* W1  = (const float*)d_in[1];
  const float* b1  = (const float*)d_in[2];
  const float* W2  = (const float*)d_in[3];
  const float* b2  = (const float*)d_in[4];
  const float* Wmu = (const float*)d_in[5];
  const float* bmu = (const float*)d_in[6];
  const float* mus = (const float*)d_in[7];
  const float* Sig = (const float*)d_in[8];
  const float* th  = (const float*)d_in[9];
  float* out = (float*)d_out;
  (void)in_sizes; (void)n_in; (void)out_size; (void)ws_size;

  // ws layout: hi/lo f16 planes, 11,141,120 bytes total
  f16* p = (f16*)d_ws;
  f16 *sh  = p; p += (size_t)B_ * 64;
  f16 *sl  = p; p += (size_t)B_ * 64;
  f16 *w1h = p; p += (size_t)A_ * 256 * 64;
  f16 *w1l = p; p += (size_t)A_ * 256 * 64;
  f16 *w2h = p; p += (size_t)A_ * 128 * 256;
  f16 *w2l = p; p += (size_t)A_ * 128 * 256;
  f16 *wmh = p; p += (size_t)A_ * 32 * 128;
  f16 *wml = p; p += (size_t)A_ * 32 * 128;
  f16 *sgh = p; p += (size_t)A_ * 32 * 32;
  f16 *sgl = p; p += (size_t)A_ * 32 * 32;

  {
    int n4;
    n4 = (B_ * 64) / 4;
    split4<<<(n4 + 255) / 256, 256, 0, stream>>>((const float4*)s, (H4*)sh, (H4*)sl, n4);
    n4 = (A_ * 256 * 64) / 4;
    split4<<<(n4 + 255) / 256, 256, 0, stream>>>((const float4*)W1, (H4*)w1h, (H4*)w1l, n4);
    n4 = (A_ * 128 * 256) / 4;
    split4<<<(n4 + 255) / 256, 256, 0, stream>>>((const float4*)W2, (H4*)w2h, (H4*)w2l, n4);
    n4 = (A_ * 32 * 128) / 4;
    split4<<<(n4 + 255) / 256, 256, 0, stream>>>((const float4*)Wmu, (H4*)wmh, (H4*)wml, n4);
    n4 = (A_ * 32 * 32) / 4;
    split4<<<(n4 + 255) / 256, 256, 0, stream>>>((const float4*)Sig, (H4*)sgh, (H4*)sgl, n4);
  }

  vae_main<<<16384, 256, 0, stream>>>(sh, sl, w1h, w1l, w2h, w2l, wmh, wml, sgh, sgl,
                                      b1, b2, bmu, mus, out);
  route_argmax<<<B_ / 64, 256, 0, stream>>>(out, th, out + (size_t)B_ * A_);
}